// Round 13
// baseline (542.561 us; speedup 1.0000x reference)
//
#include <hip/hip_runtime.h>

#define NUM_CLASSES 601
#define OUT_DIM 27
#define P_ELEMS (NUM_CLASSES * OUT_DIM)       // 16227 floats = 64908 B
#define ROWS_PER_BLOCK 8192                    // 4194304 / 512 blocks
#define ROWS_PER_CHUNK 4096                    // idx chunk staged in LDS (16 KB)
#define F4_PER_CHUNK  (ROWS_PER_CHUNK * OUT_DIM / 4)   // 27648, = 27 per thread
#define F4_PER_BLOCK  (ROWS_PER_BLOCK * OUT_DIM / 4)   // 55296 (exact, no tail)

typedef float vfloat4 __attribute__((ext_vector_type(4)));
typedef int   vint4   __attribute__((ext_vector_type(4)));

// ---------------- Kernel A: unchanged round-8 best (453.1 us total) ----------
// MEASUREMENT ROUND: A is launched TWICE (idempotent -> output bit-identical).
// second_A = dur_new - 453 gives A's true in-context dispatch cost, separating:
//   H1 (A ~165us, gather waste inside the kernel)  -> dur ~610-630
//   H6 (A ~75-105us, dur dominated by fill + harness restore-dispatch overhead)
//                                                  -> dur ~520-560
//   H2 (store/drain context ceiling, A fill-like)  -> dur ~600+, ambiguous w/H1
__global__ __launch_bounds__(1024, 8)
void trigram_probs_kernel(const int* __restrict__ idx,
                          const float* __restrict__ W,
                          float4* __restrict__ out4) {
    __shared__ float P[P_ELEMS];
    __shared__ __align__(16) int IDX[ROWS_PER_CHUNK];

    const unsigned t = threadIdx.x;
    const unsigned b = blockIdx.x;
    const unsigned row_base = b * ROWS_PER_BLOCK;

    // Chunk-0 idx loads issued first; they fly while the softmax runs.
    const vint4 c0_idx = *(const vint4*)(idx + row_base + 4u * t);

    // ---- softmax(W) -> P. Same arithmetic order as all previous rounds.
    if (t < NUM_CLASSES) {
        const float* w = W + t * OUT_DIM;
        float* p = P + t * OUT_DIM;
        float s = 0.f;
        #pragma unroll
        for (int j = 0; j < OUT_DIM; ++j) { const float v = __expf(w[j]); p[j] = v; s += v; }
        const float inv = 1.0f / s;
        #pragma unroll
        for (int j = 0; j < OUT_DIM; ++j) p[j] *= inv;
    }

    *(vint4*)(IDX + 4u * t) = c0_idx;
    __syncthreads();

    // Prefetch chunk-1 idx into registers; consumed after chunk 0.
    const vint4 c1_idx = *(const vint4*)(idx + row_base + ROWS_PER_CHUNK + 4u * t);

    float4* outb = out4 + (size_t)b * F4_PER_BLOCK;

    // ---- chunk 0: thread t handles local float4s {t + 1024j}, j=0..26.
    {
        unsigned eloc = 4u * t;
        for (int j = 0; j < 27; ++j, eloc += 4096u) {
            const unsigned r  = eloc / 27u;        // magic-multiply
            const unsigned cc = eloc - r * 27u;
            const unsigned b0 = (unsigned)IDX[r] * 27u;
            const unsigned b1 = (unsigned)IDX[r + (cc >= 24u)] * 27u;
            vfloat4 v;
            #pragma unroll
            for (int k = 0; k < 4; ++k) {
                const unsigned c = cc + (unsigned)k;
                v[k] = P[(c < 27u) ? (b0 + c) : (b1 + c - 27u)];
            }
            *(vfloat4*)(outb + t + 1024u * j) = v;
        }
    }

    __syncthreads();                               // all reads of IDX chunk 0 done
    *(vint4*)(IDX + 4u * t) = c1_idx;
    __syncthreads();

    // ---- chunk 1: identical, shifted by 4096 rows / 27648 float4s.
    {
        float4* outc = outb + F4_PER_CHUNK;
        unsigned eloc = 4u * t;
        for (int j = 0; j < 27; ++j, eloc += 4096u) {
            const unsigned r  = eloc / 27u;
            const unsigned cc = eloc - r * 27u;
            const unsigned b0 = (unsigned)IDX[r] * 27u;
            const unsigned b1 = (unsigned)IDX[r + (cc >= 24u)] * 27u;
            vfloat4 v;
            #pragma unroll
            for (int k = 0; k < 4; ++k) {
                const unsigned c = cc + (unsigned)k;
                v[k] = P[(c < 27u) ? (b0 + c) : (b1 + c - 27u)];
            }
            *(vfloat4*)(outc + t + 1024u * j) = v;
        }
    }
}

extern "C" void kernel_launch(void* const* d_in, const int* in_sizes, int n_in,
                              void* d_out, int out_size, void* d_ws, size_t ws_size,
                              hipStream_t stream) {
    const int*   idx = (const int*)d_in[0];   // bigram_idx [4194304] int32
    const float* W   = (const float*)d_in[1]; // W [601,27] float32
    float4*      out = (float4*)d_out;        // probs [4194304,27] float32

    // Launch the SAME kernel twice (idempotent; output bit-identical).
    // dur_new - 453us = one dispatch of A, measured in-context.
    trigram_probs_kernel<<<dim3(512), dim3(1024), 0, stream>>>(idx, W, out);
    trigram_probs_kernel<<<dim3(512), dim3(1024), 0, stream>>>(idx, W, out);
}

// Round 16
// 455.700 us; speedup vs baseline: 1.1906x; 1.1906x over previous
//
#include <hip/hip_runtime.h>

#define NUM_CLASSES 601
#define OUT_DIM 27
#define P_ELEMS (NUM_CLASSES * OUT_DIM)       // 16227 floats = 64908 B
#define P_F4     (P_ELEMS / 4)                 // 4056 float4, + 3 tail floats
#define ROWS_PER_BLOCK 8192                    // 4194304 / 512 blocks
#define ROWS_PER_CHUNK 4096                    // idx chunk staged in LDS (16 KB)
#define F4_PER_CHUNK  (ROWS_PER_CHUNK * OUT_DIM / 4)   // 27648, = 27 per thread
#define F4_PER_BLOCK  (ROWS_PER_BLOCK * OUT_DIM / 4)   // 55296 (exact, no tail)

typedef float vfloat4 __attribute__((ext_vector_type(4)));
typedef int   vint4   __attribute__((ext_vector_type(4)));

// Kernel S: softmax each W row -> workspace. Same arithmetic order as the old
// in-block preamble -> bit-identical P values. Runs once, 3 blocks, ~2 us.
__global__ __launch_bounds__(256)
void softmax_rows_kernel(const float* __restrict__ W, float* __restrict__ P) {
    const unsigned row = blockIdx.x * 256u + threadIdx.x;
    if (row >= NUM_CLASSES) return;
    const float* w = W + row * OUT_DIM;
    float* p = P + row * OUT_DIM;
    float s = 0.f;
    #pragma unroll
    for (int j = 0; j < OUT_DIM; ++j) { const float v = __expf(w[j]); p[j] = v; s += v; }
    const float inv = 1.0f / s;
    #pragma unroll
    for (int j = 0; j < OUT_DIM; ++j) p[j] *= inv;
}

// Kernel A': round-8 gather (89.5 us warm, measured r13) with the serial
// per-block softmax preamble (27 stride-108B W passes + 54 transcendentals,
// fully exposed before the barrier) replaced by a coalesced float4 copy of the
// precomputed table (4 loads/thread, hidden under IDX staging). Target: close
// part of the 90 -> 72 us store-floor gap.
__global__ __launch_bounds__(1024, 8)
void trigram_probs_kernel(const int* __restrict__ idx,
                          const float* __restrict__ Pws,
                          float4* __restrict__ out4) {
    __shared__ __align__(16) float P[P_ELEMS];
    __shared__ __align__(16) int IDX[ROWS_PER_CHUNK];

    const unsigned t = threadIdx.x;
    const unsigned b = blockIdx.x;
    const unsigned row_base = b * ROWS_PER_BLOCK;

    // Issue chunk-0 idx loads first; they fly while P streams in.
    const vint4 c0_idx = *(const vint4*)(idx + row_base + 4u * t);

    // ---- P table: coalesced global->LDS copy (4056 float4 + 3 tail floats).
    {
        const vfloat4* __restrict__ src = (const vfloat4*)Pws;
        vfloat4* __restrict__ dst = (vfloat4*)P;
        #pragma unroll
        for (int k = 0; k < 4; ++k) {
            const unsigned i = t + 1024u * (unsigned)k;
            if (i < (unsigned)P_F4) dst[i] = src[i];
        }
        if (t < 3u) P[P_F4 * 4u + t] = Pws[P_F4 * 4u + t];
    }

    *(vint4*)(IDX + 4u * t) = c0_idx;
    __syncthreads();

    // Prefetch chunk-1 idx into registers; consumed after chunk 0.
    const vint4 c1_idx = *(const vint4*)(idx + row_base + ROWS_PER_CHUNK + 4u * t);

    float4* outb = out4 + (size_t)b * F4_PER_BLOCK;

    // ---- chunk 0: thread t handles local float4s {t + 1024j}, j=0..26.
    {
        unsigned eloc = 4u * t;
        for (int j = 0; j < 27; ++j, eloc += 4096u) {
            const unsigned r  = eloc / 27u;        // magic-multiply
            const unsigned cc = eloc - r * 27u;
            const unsigned b0 = (unsigned)IDX[r] * 27u;
            const unsigned b1 = (unsigned)IDX[r + (cc >= 24u)] * 27u;
            vfloat4 v;
            #pragma unroll
            for (int k = 0; k < 4; ++k) {
                const unsigned c = cc + (unsigned)k;
                v[k] = P[(c < 27u) ? (b0 + c) : (b1 + c - 27u)];
            }
            *(vfloat4*)(outb + t + 1024u * j) = v;
        }
    }

    __syncthreads();                               // all reads of IDX chunk 0 done
    *(vint4*)(IDX + 4u * t) = c1_idx;
    __syncthreads();

    // ---- chunk 1: identical, shifted by 4096 rows / 27648 float4s.
    {
        float4* outc = outb + F4_PER_CHUNK;
        unsigned eloc = 4u * t;
        for (int j = 0; j < 27; ++j, eloc += 4096u) {
            const unsigned r  = eloc / 27u;
            const unsigned cc = eloc - r * 27u;
            const unsigned b0 = (unsigned)IDX[r] * 27u;
            const unsigned b1 = (unsigned)IDX[r + (cc >= 24u)] * 27u;
            vfloat4 v;
            #pragma unroll
            for (int k = 0; k < 4; ++k) {
                const unsigned c = cc + (unsigned)k;
                v[k] = P[(c < 27u) ? (b0 + c) : (b1 + c - 27u)];
            }
            *(vfloat4*)(outc + t + 1024u * j) = v;
        }
    }
}

extern "C" void kernel_launch(void* const* d_in, const int* in_sizes, int n_in,
                              void* d_out, int out_size, void* d_ws, size_t ws_size,
                              hipStream_t stream) {
    const int*   idx = (const int*)d_in[0];   // bigram_idx [4194304] int32
    const float* W   = (const float*)d_in[1]; // W [601,27] float32
    float4*      out = (float4*)d_out;        // probs [4194304,27] float32
    float*       Pws = (float*)d_ws;          // 64908 B softmax table in workspace

    // S once (same stream -> ordered before A'), then the gather kernel.
    softmax_rows_kernel<<<dim3(3), dim3(256), 0, stream>>>(W, Pws);
    trigram_probs_kernel<<<dim3(512), dim3(1024), 0, stream>>>(idx, Pws, out);
}